// Round 4
// baseline (306.843 us; speedup 1.0000x reference)
//
#include <hip/hip_runtime.h>
#include <hip/hip_bf16.h>

// MultiHeadBatchedMixers, three-phase structure:
//   Prepack: w1t,w2t,x,b1,b2 -> bf16 in ws (removes in-loop cvt + halves re-read bytes)
//   Kernel A: H[bhk][c][e] = GELU(W1c @ X @ W1t^T + B1)   (bf16 ws, no barriers, 18KB LDS)
//   Kernel B: out[bh][co][n] = sum_k wk*(W2c @ (H_k @ W2t^T) + B2)  (no barriers)
// bf16 MFMA 16x16x32, f32 accumulate.

namespace {
constexpr int NHEAD = 12, NTOK = 256, HDIM = 64, HIDD = 512, NBATCH = 32, TOPK = 2;
constexpr int NCHAIN = NBATCH * NHEAD * TOPK;  // 768

// per-wave T1^T [32 e][64 d] bf16, pitch +16B
constexpr int P_T1 = HDIM * 2 + 16;   // 144
constexpr int T1_W = 32 * P_T1;       // 4608
constexpr int SMA_TOTAL = 4 * T1_W;   // 18432
// per-wave T3^T [16 n][64 c]
constexpr int P_T3 = HDIM * 2 + 16;   // 144
constexpr int T3_W = 16 * P_T3;       // 2304
constexpr int SMB_TOTAL = 4 * T3_W;   // 9216

// ws layout (elements are bf16/short unless noted)
constexpr size_t SZ_H    = (size_t)NCHAIN * HDIM * HIDD;          // 25,165,824 el
constexpr size_t OFF_H   = 0;
constexpr size_t OFF_W1T = OFF_H + SZ_H;
constexpr size_t SZ_W1T  = (size_t)8 * NHEAD * HIDD * NTOK;       // 12,582,912
constexpr size_t OFF_W2T = OFF_W1T + SZ_W1T;
constexpr size_t SZ_W2T  = (size_t)8 * NHEAD * NTOK * HIDD;
constexpr size_t OFF_X   = OFF_W2T + SZ_W2T;
constexpr size_t SZ_X    = (size_t)NBATCH * NHEAD * HDIM * NTOK;  // 6,291,456
constexpr size_t OFF_B1  = OFF_X + SZ_X;
constexpr size_t SZ_B1   = (size_t)8 * NHEAD * HDIM * HIDD;
constexpr size_t OFF_B2  = OFF_B1 + SZ_B1;
constexpr size_t SZ_B2   = (size_t)8 * NHEAD * HDIM * NTOK;
constexpr size_t NEED_PP = (OFF_B2 + SZ_B2) * 2;                  // bytes: 138,412,032
}

typedef float f32x4 __attribute__((ext_vector_type(4)));
typedef short bf16x8 __attribute__((ext_vector_type(8)));
typedef short bf16x4 __attribute__((ext_vector_type(4)));

#define MFMA16(a, b, c) __builtin_amdgcn_mfma_f32_16x16x32_bf16((a), (b), (c), 0, 0, 0)

__device__ __forceinline__ short f2bf(float f) {
  union { float f; unsigned u; } v; v.f = f;
  unsigned r = v.u + 0x7fffu + ((v.u >> 16) & 1u);
  return (short)(r >> 16);
}

__device__ __forceinline__ bf16x8 ld_gfrag(const float* p) {
  float4 a = *(const float4*)p;
  float4 b = *(const float4*)(p + 4);
  bf16x8 r;
  r[0] = f2bf(a.x); r[1] = f2bf(a.y); r[2] = f2bf(a.z); r[3] = f2bf(a.w);
  r[4] = f2bf(b.x); r[5] = f2bf(b.y); r[6] = f2bf(b.z); r[7] = f2bf(b.w);
  return r;
}

__device__ __forceinline__ f32x4 bf4f(bf16x4 v) {
  f32x4 r;
  #pragma unroll
  for (int i = 0; i < 4; ++i) {
    union { unsigned u; float f; } t;
    t.u = ((unsigned)(unsigned short)v[i]) << 16;
    r[i] = t.f;
  }
  return r;
}

__device__ __forceinline__ float gelu_tanh(float x) {
  float u = 0.7978845608028654f * x * (1.0f + 0.044715f * x * x);
  return x / (1.0f + __expf(-2.0f * u));
}

// ---------------- Prepack: f32 -> bf16, 8 elems/thread/iter ----------------
__global__ void cvt_bf16(const float* __restrict__ src, short* __restrict__ dst, int n8) {
  int i = blockIdx.x * blockDim.x + threadIdx.x;
  int stride = gridDim.x * blockDim.x;
  for (; i < n8; i += stride)
    *((bf16x8*)dst + i) = ld_gfrag(src + (size_t)i * 8);
}

// ---------------- Kernel A ----------------
// grid = 768*4; bhk = bx>>2, e-block = (bx&3)*128. Wave w owns e-rows [e0, e0+32).
template <bool PP>
__global__ __launch_bounds__(256) void mixer_h_kernel(
    const float* __restrict__ x, const short* __restrict__ xb,
    const int* __restrict__ eidx,
    const float* __restrict__ w1t, const short* __restrict__ w1tb,
    const float* __restrict__ w1c,
    const float* __restrict__ b1, const short* __restrict__ b1b,
    short* __restrict__ hws) {
  __shared__ __align__(16) char smem[SMA_TOTAL];
  const int bx = blockIdx.x;
  const int bhk = bx >> 2, eblk = bx & 3;
  const int h = (bhk >> 1) % NHEAD;
  const int tid = threadIdx.x, w = tid >> 6, lane = tid & 63, lr = lane & 15, lg = lane >> 4;

  const int e = eidx[bhk];
  const size_t eh = (size_t)e * NHEAD + h;
  const size_t bhoff = (size_t)(bhk >> 1) * HDIM * NTOK;
  short* H = hws + (size_t)bhk * HDIM * HIDD;

  const int e0 = eblk * 128 + w * 32;

  // MFMA1: T1[d][e] = sum_n X[d,n]*W1t[e,n];  A=X (m=d), B=W1t (n=e), k=n
  f32x4 acc1[2][4];
  #pragma unroll
  for (int et = 0; et < 2; ++et)
    #pragma unroll
    for (int dt = 0; dt < 4; ++dt) acc1[et][dt] = (f32x4){0.f, 0.f, 0.f, 0.f};
  #pragma unroll
  for (int ks = 0; ks < 8; ++ks) {
    bf16x8 w0, w1v;
    if (PP) {
      const short* W1Tb = w1tb + eh * HIDD * NTOK;
      w0  = *(const bf16x8*)(W1Tb + (size_t)(e0 + lr) * NTOK + ks * 32 + lg * 8);
      w1v = *(const bf16x8*)(W1Tb + (size_t)(e0 + 16 + lr) * NTOK + ks * 32 + lg * 8);
    } else {
      const float* W1T = w1t + eh * HIDD * NTOK;
      w0  = ld_gfrag(W1T + (size_t)(e0 + lr) * NTOK + ks * 32 + lg * 8);
      w1v = ld_gfrag(W1T + (size_t)(e0 + 16 + lr) * NTOK + ks * 32 + lg * 8);
    }
    #pragma unroll
    for (int dt = 0; dt < 4; ++dt) {
      bf16x8 xf;
      if (PP) xf = *(const bf16x8*)(xb + bhoff + (size_t)(dt * 16 + lr) * NTOK + ks * 32 + lg * 8);
      else    xf = ld_gfrag(x + bhoff + (size_t)(dt * 16 + lr) * NTOK + ks * 32 + lg * 8);
      acc1[0][dt] = MFMA16(xf, w0, acc1[0][dt]);
      acc1[1][dt] = MFMA16(xf, w1v, acc1[1][dt]);
    }
  }

  // relayout T1^T via wave-private LDS (col=e=lr, row=d=dt*16+lg*4+i) -> [e][d] rows
  char* t1 = smem + w * T1_W;
  #pragma unroll
  for (int et = 0; et < 2; ++et)
    #pragma unroll
    for (int dt = 0; dt < 4; ++dt) {
      bf16x4 p;
      #pragma unroll
      for (int i = 0; i < 4; ++i) p[i] = f2bf(acc1[et][dt][i]);
      *(bf16x4*)(t1 + (et * 16 + lr) * P_T1 + (dt * 16 + lg * 4) * 2) = p;
    }

  // MFMA2: T2^T[e][c] = sum_d T1^T[e,d]*W1c[c,d] + B1;  A=T1^T (LDS), B=W1c (global f32)
  const float* W1C = w1c + eh * HDIM * HDIM;
  f32x4 acc2[2][4];
  #pragma unroll
  for (int et = 0; et < 2; ++et)
    #pragma unroll
    for (int ct = 0; ct < 4; ++ct) {
      if (PP) {
        bf16x4 bb = *(const bf16x4*)(b1b + eh * HDIM * HIDD + (size_t)(ct * 16 + lr) * HIDD + e0 + et * 16 + lg * 4);
        acc2[et][ct] = bf4f(bb);
      } else {
        acc2[et][ct] = *(const f32x4*)(b1 + eh * HDIM * HIDD + (size_t)(ct * 16 + lr) * HIDD + e0 + et * 16 + lg * 4);
      }
    }
  #pragma unroll
  for (int ks = 0; ks < 2; ++ks) {
    bf16x8 a[2];
    #pragma unroll
    for (int et = 0; et < 2; ++et)
      a[et] = *(const bf16x8*)(t1 + (et * 16 + lr) * P_T1 + (ks * 32 + lg * 8) * 2);
    #pragma unroll
    for (int ct = 0; ct < 4; ++ct) {
      bf16x8 bfr = ld_gfrag(W1C + (size_t)(ct * 16 + lr) * HDIM + ks * 32 + lg * 8);
      #pragma unroll
      for (int et = 0; et < 2; ++et) acc2[et][ct] = MFMA16(a[et], bfr, acc2[et][ct]);
    }
  }

  // GELU + store H[c][e] (col=c=lr, row=e=lg*4+i) -> 8B stores
  #pragma unroll
  for (int et = 0; et < 2; ++et)
    #pragma unroll
    for (int ct = 0; ct < 4; ++ct) {
      bf16x4 g;
      #pragma unroll
      for (int i = 0; i < 4; ++i) g[i] = f2bf(gelu_tanh(acc2[et][ct][i]));
      *(bf16x4*)(H + (size_t)(ct * 16 + lr) * HIDD + e0 + et * 16 + lg * 4) = g;
    }
}

// ---------------- Kernel B ----------------
// grid = 384*4; bh = bx>>2, n-tile = (bx&3)*64. Wave w owns n in [nb, nb+16).
template <bool PP>
__global__ __launch_bounds__(256) void mixer_out_kernel(
    const int* __restrict__ eidx, const float* __restrict__ ewt,
    const float* __restrict__ w2t, const short* __restrict__ w2tb,
    const float* __restrict__ w2c,
    const float* __restrict__ b2, const short* __restrict__ b2b,
    const short* __restrict__ hws, float* __restrict__ out) {
  __shared__ __align__(16) char smem[SMB_TOTAL];
  const int bx = blockIdx.x;
  const int bh = bx >> 2, h = bh % NHEAD;
  const int tid = threadIdx.x, w = tid >> 6, lane = tid & 63, lr = lane & 15, lg = lane >> 4;
  const int nb = (bx & 3) * 64 + w * 16;
  char* t3 = smem + w * T3_W;
  float* OUT = out + (size_t)bh * HDIM * NTOK;

  f32x4 accO[4];
  #pragma unroll
  for (int ct = 0; ct < 4; ++ct) accO[ct] = (f32x4){0.f, 0.f, 0.f, 0.f};

  for (int k = 0; k < TOPK; ++k) {
    const int e = eidx[bh * TOPK + k];
    const float wk = ewt[bh * TOPK + k];
    const size_t eh = (size_t)e * NHEAD + h;
    const float* W2C = w2c + eh * HDIM * HDIM;
    const short* Hk = hws + (size_t)(bh * TOPK + k) * HDIM * HIDD;

    // MFMA3: T3[c][n] = sum_e H[c,e]*W2t[n,e];  A=H (m=c), B=W2t (n=n), k=e
    f32x4 acc3[4];
    #pragma unroll
    for (int ct = 0; ct < 4; ++ct) acc3[ct] = (f32x4){0.f, 0.f, 0.f, 0.f};
    #pragma unroll 4
    for (int ks = 0; ks < 16; ++ks) {
      bf16x8 bfr;
      if (PP) bfr = *(const bf16x8*)(w2tb + eh * NTOK * HIDD + (size_t)(nb + lr) * HIDD + ks * 32 + lg * 8);
      else    bfr = ld_gfrag(w2t + eh * NTOK * HIDD + (size_t)(nb + lr) * HIDD + ks * 32 + lg * 8);
      #pragma unroll
      for (int ct = 0; ct < 4; ++ct) {
        bf16x8 a = *(const bf16x8*)(Hk + (size_t)(ct * 16 + lr) * HIDD + ks * 32 + lg * 8);
        acc3[ct] = MFMA16(a, bfr, acc3[ct]);
      }
    }

    // relayout T3^T via wave-private LDS (col=n=lr, row=c=ct*16+lg*4+i) -> [n][c]
    #pragma unroll
    for (int ct = 0; ct < 4; ++ct) {
      bf16x4 p;
      #pragma unroll
      for (int i = 0; i < 4; ++i) p[i] = f2bf(acc3[ct][i]);
      *(bf16x4*)(t3 + lr * P_T3 + (ct * 16 + lg * 4) * 2) = p;
    }

    // MFMA4: OUT^T[n][co] = sum_c T3^T[n,c]*W2c[co,c];  A=T3^T (m=n), B=W2c (n=co)
    f32x4 acc4[4];
    #pragma unroll
    for (int cot = 0; cot < 4; ++cot) acc4[cot] = (f32x4){0.f, 0.f, 0.f, 0.f};
    #pragma unroll
    for (int ks = 0; ks < 2; ++ks) {
      bf16x8 a = *(const bf16x8*)(t3 + lr * P_T3 + (ks * 32 + lg * 8) * 2);
      #pragma unroll
      for (int cot = 0; cot < 4; ++cot) {
        bf16x8 bfr = ld_gfrag(W2C + (size_t)(cot * 16 + lr) * HDIM + ks * 32 + lg * 8);
        acc4[cot] = MFMA16(a, bfr, acc4[cot]);
      }
    }

    // weighted accumulate: accO += wk*(acc4 + B2)  (col=co=lr, row=n=lg*4+i)
    #pragma unroll
    for (int cot = 0; cot < 4; ++cot) {
      f32x4 bb;
      if (PP) bb = bf4f(*(const bf16x4*)(b2b + eh * HDIM * NTOK + (size_t)(cot * 16 + lr) * NTOK + nb + lg * 4));
      else    bb = *(const f32x4*)(b2 + eh * HDIM * NTOK + (size_t)(cot * 16 + lr) * NTOK + nb + lg * 4);
      #pragma unroll
      for (int i = 0; i < 4; ++i) accO[cot][i] += wk * (acc4[cot][i] + bb[i]);
    }
  }

  // store (each (co,n) written exactly once across the grid)
  #pragma unroll
  for (int cot = 0; cot < 4; ++cot)
    *(f32x4*)(OUT + (size_t)(cot * 16 + lr) * NTOK + nb + lg * 4) = accO[cot];
}

extern "C" void kernel_launch(void* const* d_in, const int* in_sizes, int n_in,
                              void* d_out, int out_size, void* d_ws, size_t ws_size,
                              hipStream_t stream) {
  const float* x   = (const float*)d_in[0];
  const int*   ei  = (const int*)d_in[1];
  const float* ew  = (const float*)d_in[2];
  const float* w1t = (const float*)d_in[3];
  const float* w1c = (const float*)d_in[4];
  const float* b1  = (const float*)d_in[5];
  const float* w2t = (const float*)d_in[6];
  const float* w2c = (const float*)d_in[7];
  const float* b2  = (const float*)d_in[8];
  float* out = (float*)d_out;
  short* ws = (short*)d_ws;

  short* hws  = ws + OFF_H;
  short* w1tb = ws + OFF_W1T;
  short* w2tb = ws + OFF_W2T;
  short* xb   = ws + OFF_X;
  short* b1b  = ws + OFF_B1;
  short* b2b  = ws + OFF_B2;

  const bool pp = ws_size >= NEED_PP;

  if (pp) {
    auto cvt = [&](const float* s, short* d, size_t n) {
      int n8 = (int)(n / 8);
      int grid = (n8 + 255) / 256; if (grid > 2048) grid = 2048;
      cvt_bf16<<<dim3(grid), dim3(256), 0, stream>>>(s, d, n8);
    };
    cvt(w1t, w1tb, SZ_W1T);
    cvt(w2t, w2tb, SZ_W2T);
    cvt(x,   xb,   SZ_X);
    cvt(b1,  b1b,  SZ_B1);
    cvt(b2,  b2b,  SZ_B2);
    mixer_h_kernel<true><<<dim3(NCHAIN * 4), dim3(256), 0, stream>>>(
        x, xb, ei, w1t, w1tb, w1c, b1, b1b, hws);
    mixer_out_kernel<true><<<dim3(NBATCH * NHEAD * 4), dim3(256), 0, stream>>>(
        ei, ew, w2t, w2tb, w2c, b2, b2b, hws, out);
  } else {
    mixer_h_kernel<false><<<dim3(NCHAIN * 4), dim3(256), 0, stream>>>(
        x, xb, ei, w1t, w1tb, w1c, b1, b1b, hws);
    mixer_out_kernel<false><<<dim3(NBATCH * NHEAD * 4), dim3(256), 0, stream>>>(
        ei, ew, w2t, w2tb, w2c, b2, b2b, hws, out);
  }
}